// Round 1
// baseline (439.105 us; speedup 1.0000x reference)
//
#include <hip/hip_runtime.h>

#define NN 50000
#define NE 625000

// ---------------- CSR build ----------------

__global__ void deg_kernel(const int* __restrict__ dst, int* __restrict__ deg, int e) {
    int i = blockIdx.x * blockDim.x + threadIdx.x;
    if (i < e) atomicAdd(&deg[dst[i]], 1);
}

__global__ void scan_local(const int* __restrict__ deg, int* __restrict__ incl,
                           int* __restrict__ bsum, int n) {
    __shared__ int s[1024];
    int i = blockIdx.x * 1024 + threadIdx.x;
    int v = (i < n) ? deg[i] : 0;
    s[threadIdx.x] = v;
    __syncthreads();
    for (int off = 1; off < 1024; off <<= 1) {
        int t = (threadIdx.x >= (unsigned)off) ? s[threadIdx.x - off] : 0;
        __syncthreads();
        s[threadIdx.x] += t;
        __syncthreads();
    }
    if (i < n) incl[i] = s[threadIdx.x];
    if (threadIdx.x == 1023) bsum[blockIdx.x] = s[1023];
}

__global__ void scan_bases(const int* __restrict__ bsum, int* __restrict__ bbase, int nb) {
    int lane = threadIdx.x;
    int v = (lane < nb) ? bsum[lane] : 0;
    int orig = v;
    for (int off = 1; off < 64; off <<= 1) {
        int t = __shfl_up(v, off, 64);
        if (lane >= off) v += t;
    }
    if (lane < nb) bbase[lane] = v - orig;
}

__global__ void scan_final(const int* __restrict__ deg, const int* __restrict__ incl,
                           const int* __restrict__ bbase, int* __restrict__ rowstart,
                           int* __restrict__ cursor, float* __restrict__ inv, int n, int e) {
    int i = blockIdx.x * 1024 + threadIdx.x;
    if (i < n) {
        int v = deg[i];
        int excl = bbase[blockIdx.x] + incl[i] - v;
        rowstart[i] = excl;
        cursor[i] = excl;
        inv[i] = 1.0f / (float)max(v, 1);
    }
    if (i == 0) rowstart[n] = e;
}

__global__ void fill_kernel(const int* __restrict__ src, const int* __restrict__ dst,
                            int* __restrict__ cursor, int* __restrict__ col, int e) {
    int i = blockIdx.x * blockDim.x + threadIdx.x;
    if (i < e) {
        int p = atomicAdd(&cursor[dst[i]], 1);
        col[p] = src[i];
    }
}

// ---------------- fp32 tiled GEMM: C[M,NO] = A[M,K] @ W[K,NO] (+bias) ----------------
// BM=BN=BK=64, 256 threads, each thread 4x4 outputs.

__global__ __launch_bounds__(256)
void gemm_kernel(const float* __restrict__ A, const float* __restrict__ W,
                 const float* __restrict__ bias, float* __restrict__ C,
                 int M, int K, int NO) {
    __shared__ float As[64][68];  // [k][m], transposed
    __shared__ float Bs[64][68];  // [k][n]
    int m0 = blockIdx.x * 64;
    int n0 = blockIdx.y * 64;
    int t = threadIdx.x;
    int tm = t & 15, tn = t >> 4;
    float acc[4][4] = {};

    for (int kc = 0; kc < K; kc += 64) {
        // A tile: rows m0..m0+63, cols kc..kc+63 -> As[k][m]
        {
            int c = t & 15;   // k float4 group (4 k-values)
            int i0 = t >> 4;  // starting row
            #pragma unroll
            for (int ii = 0; ii < 4; ++ii) {
                int i = i0 + ii * 16;
                int gm = m0 + i;
                float4 va = make_float4(0.f, 0.f, 0.f, 0.f);
                if (gm < M) va = *(const float4*)&A[(size_t)gm * K + kc + c * 4];
                As[c * 4 + 0][i] = va.x;
                As[c * 4 + 1][i] = va.y;
                As[c * 4 + 2][i] = va.z;
                As[c * 4 + 3][i] = va.w;
            }
            // B tile: rows kc..kc+63, cols n0..n0+63 -> Bs[k][n]
            int n4 = t & 15;
            int k0 = t >> 4;
            #pragma unroll
            for (int ii = 0; ii < 4; ++ii) {
                int k = k0 + ii * 16;
                *(float4*)&Bs[k][n4 * 4] = *(const float4*)&W[(size_t)(kc + k) * NO + n0 + n4 * 4];
            }
        }
        __syncthreads();
        #pragma unroll 8
        for (int k = 0; k < 64; ++k) {
            float4 a = *(const float4*)&As[k][tm * 4];
            float4 b = *(const float4*)&Bs[k][tn * 4];
            acc[0][0] += a.x * b.x; acc[0][1] += a.x * b.y; acc[0][2] += a.x * b.z; acc[0][3] += a.x * b.w;
            acc[1][0] += a.y * b.x; acc[1][1] += a.y * b.y; acc[1][2] += a.y * b.z; acc[1][3] += a.y * b.w;
            acc[2][0] += a.z * b.x; acc[2][1] += a.z * b.y; acc[2][2] += a.z * b.z; acc[2][3] += a.z * b.w;
            acc[3][0] += a.w * b.x; acc[3][1] += a.w * b.y; acc[3][2] += a.w * b.z; acc[3][3] += a.w * b.w;
        }
        __syncthreads();
    }

    float4 bv = make_float4(0.f, 0.f, 0.f, 0.f);
    if (bias) bv = *(const float4*)&bias[n0 + tn * 4];
    #pragma unroll
    for (int r = 0; r < 4; ++r) {
        int gm = m0 + tm * 4 + r;
        if (gm < M) {
            float4 o;
            o.x = acc[r][0] + bv.x;
            o.y = acc[r][1] + bv.y;
            o.z = acc[r][2] + bv.z;
            o.w = acc[r][3] + bv.w;
            *(float4*)&C[(size_t)gm * NO + n0 + tn * 4] = o;
        }
    }
}

// ---------------- aggregation: out[v] = relu?(inv[v]*sum_{u in N(v)} y[u] + z[v]) ----------------
// one wave per destination node

__global__ __launch_bounds__(256)
void agg_kernel(const float* __restrict__ y, const float* __restrict__ z,
                const int* __restrict__ rowstart, const int* __restrict__ col,
                const float* __restrict__ inv, float* __restrict__ out,
                int n, int C, int do_relu) {
    int gw = (int)((blockIdx.x * blockDim.x + threadIdx.x) >> 6);
    int lane = threadIdx.x & 63;
    if (gw >= n) return;
    int beg = rowstart[gw], end = rowstart[gw + 1];
    float iv = inv[gw];
    if (C == 128) {
        float ax = 0.f, ay = 0.f;
        for (int e = beg; e < end; ++e) {
            int u = col[e];  // wave-uniform
            float2 yv = *(const float2*)&y[(size_t)u * 128 + lane * 2];
            ax += yv.x; ay += yv.y;
        }
        float2 zv = *(const float2*)&z[(size_t)gw * 128 + lane * 2];
        float ox = ax * iv + zv.x;
        float oy = ay * iv + zv.y;
        if (do_relu) { ox = fmaxf(ox, 0.f); oy = fmaxf(oy, 0.f); }
        *(float2*)&out[(size_t)gw * 128 + lane * 2] = make_float2(ox, oy);
    } else {
        float a = 0.f;
        for (int e = beg; e < end; ++e) {
            int u = col[e];
            a += y[(size_t)u * 64 + lane];
        }
        float o = a * iv + z[(size_t)gw * 64 + lane];
        if (do_relu) o = fmaxf(o, 0.f);
        out[(size_t)gw * 64 + lane] = o;
    }
}

// ---------------- launch ----------------

extern "C" void kernel_launch(void* const* d_in, const int* in_sizes, int n_in,
                              void* d_out, int out_size, void* d_ws, size_t ws_size,
                              hipStream_t stream) {
    const float* x   = (const float*)d_in[0];
    const int*   ei  = (const int*)d_in[1];
    const int*   src = ei;
    const int*   dst = ei + NE;
    const float* Wl1 = (const float*)d_in[2];
    const float* Wr1 = (const float*)d_in[3];
    const float* b1  = (const float*)d_in[4];
    const float* Wl2 = (const float*)d_in[5];
    const float* Wr2 = (const float*)d_in[6];
    const float* b2  = (const float*)d_in[7];
    const float* Wl3 = (const float*)d_in[8];
    const float* Wr3 = (const float*)d_in[9];
    const float* b3  = (const float*)d_in[10];
    float* out = (float*)d_out;

    char* ws = (char*)d_ws;
    size_t off = 0;
    auto alloc = [&](size_t bytes) -> void* {
        void* p = ws + off;
        off += (bytes + 255) & ~(size_t)255;
        return p;
    };

    int*   deg      = (int*)alloc(NN * 4);
    int*   incl     = (int*)alloc(NN * 4);
    int*   bsum     = (int*)alloc(64 * 4);
    int*   bbase    = (int*)alloc(64 * 4);
    int*   rowstart = (int*)alloc((NN + 1) * 4);
    int*   cursor   = (int*)alloc(NN * 4);
    int*   col      = (int*)alloc(NE * 4);
    float* inv      = (float*)alloc(NN * 4);
    float* y        = (float*)alloc((size_t)NN * 128 * 4);
    float* z        = (float*)alloc((size_t)NN * 128 * 4);
    float* h        = (float*)alloc((size_t)NN * 128 * 4);

    int nb = (NN + 1023) / 1024;

    hipMemsetAsync(deg, 0, NN * 4, stream);
    deg_kernel<<<(NE + 255) / 256, 256, 0, stream>>>(dst, deg, NE);
    scan_local<<<nb, 1024, 0, stream>>>(deg, incl, bsum, NN);
    scan_bases<<<1, 64, 0, stream>>>(bsum, bbase, nb);
    scan_final<<<nb, 1024, 0, stream>>>(deg, incl, bbase, rowstart, cursor, inv, NN, NE);
    fill_kernel<<<(NE + 255) / 256, 256, 0, stream>>>(src, dst, cursor, col, NE);

    dim3 g12((NN + 63) / 64, 2);
    dim3 g3((NN + 63) / 64, 1);
    int aggBlocks = (NN * 64) / 256;

    // layer 1
    gemm_kernel<<<g12, 256, 0, stream>>>(x, Wl1, nullptr, y, NN, 128, 128);
    gemm_kernel<<<g12, 256, 0, stream>>>(x, Wr1, b1, z, NN, 128, 128);
    agg_kernel<<<aggBlocks, 256, 0, stream>>>(y, z, rowstart, col, inv, h, NN, 128, 1);
    // layer 2
    gemm_kernel<<<g12, 256, 0, stream>>>(h, Wl2, nullptr, y, NN, 128, 128);
    gemm_kernel<<<g12, 256, 0, stream>>>(h, Wr2, b2, z, NN, 128, 128);
    agg_kernel<<<aggBlocks, 256, 0, stream>>>(y, z, rowstart, col, inv, h, NN, 128, 1);
    // layer 3
    gemm_kernel<<<g3, 256, 0, stream>>>(h, Wl3, nullptr, y, NN, 128, 64);
    gemm_kernel<<<g3, 256, 0, stream>>>(h, Wr3, b3, z, NN, 128, 64);
    agg_kernel<<<aggBlocks, 256, 0, stream>>>(y, z, rowstart, col, inv, out, NN, 64, 0);
}

// Round 2
// 265.490 us; speedup vs baseline: 1.6539x; 1.6539x over previous
//
#include <hip/hip_runtime.h>

#define NN 50000
#define NE 625000

typedef __bf16 bf16_8 __attribute__((ext_vector_type(8)));
typedef __bf16 bf16_4 __attribute__((ext_vector_type(4)));
typedef __bf16 bf16_2 __attribute__((ext_vector_type(2)));
typedef float f32_4 __attribute__((ext_vector_type(4)));

// ---------------- CSR build ----------------

__global__ void deg_kernel(const int* __restrict__ dst, int* __restrict__ deg, int e) {
    int i = blockIdx.x * blockDim.x + threadIdx.x;
    if (i < e) atomicAdd(&deg[dst[i]], 1);
}

__global__ void scan_local(const int* __restrict__ deg, int* __restrict__ incl,
                           int* __restrict__ bsum, int n) {
    __shared__ int s[1024];
    int i = blockIdx.x * 1024 + threadIdx.x;
    int v = (i < n) ? deg[i] : 0;
    s[threadIdx.x] = v;
    __syncthreads();
    for (int off = 1; off < 1024; off <<= 1) {
        int t = (threadIdx.x >= (unsigned)off) ? s[threadIdx.x - off] : 0;
        __syncthreads();
        s[threadIdx.x] += t;
        __syncthreads();
    }
    if (i < n) incl[i] = s[threadIdx.x];
    if (threadIdx.x == 1023) bsum[blockIdx.x] = s[1023];
}

__global__ void scan_bases(const int* __restrict__ bsum, int* __restrict__ bbase, int nb) {
    int lane = threadIdx.x;
    int v = (lane < nb) ? bsum[lane] : 0;
    int orig = v;
    for (int off = 1; off < 64; off <<= 1) {
        int t = __shfl_up(v, off, 64);
        if (lane >= off) v += t;
    }
    if (lane < nb) bbase[lane] = v - orig;
}

__global__ void scan_final(const int* __restrict__ deg, const int* __restrict__ incl,
                           const int* __restrict__ bbase, int* __restrict__ rowstart,
                           int* __restrict__ cursor, float* __restrict__ inv, int n, int e) {
    int i = blockIdx.x * 1024 + threadIdx.x;
    if (i < n) {
        int v = deg[i];
        int excl = bbase[blockIdx.x] + incl[i] - v;
        rowstart[i] = excl;
        cursor[i] = excl;
        inv[i] = 1.0f / (float)max(v, 1);
    }
    if (i == 0) rowstart[n] = e;
}

__global__ void fill_kernel(const int* __restrict__ src, const int* __restrict__ dst,
                            int* __restrict__ cursor, int* __restrict__ col, int e) {
    int i = blockIdx.x * blockDim.x + threadIdx.x;
    if (i < e) {
        int p = atomicAdd(&cursor[dst[i]], 1);
        col[p] = src[i];
    }
}

// ---------------- converts ----------------

// x fp32 -> bf16, n elements (n % 4 == 0)
__global__ void convx_kernel(const float* __restrict__ x, __bf16* __restrict__ xb, int n) {
    int i = (blockIdx.x * blockDim.x + threadIdx.x) * 4;
    if (i < n) {
        float4 v = *(const float4*)&x[i];
        bf16_4 o;
        o.x = (__bf16)v.x; o.y = (__bf16)v.y; o.z = (__bf16)v.z; o.w = (__bf16)v.w;
        *(bf16_4*)&xb[i] = o;
    }
}

// Wl[K=128][NO], Wr[K=128][NO] fp32 -> Wt[2*NO][128] bf16 transposed concat
__global__ void convw_kernel(const float* __restrict__ Wl, const float* __restrict__ Wr,
                             __bf16* __restrict__ Wt, int NO) {
    int i = blockIdx.x * blockDim.x + threadIdx.x;
    if (i >= 2 * NO * 128) return;
    int k = i & 127;
    int n = i >> 7;
    const float* W = (n < NO) ? Wl : Wr;
    int nn = (n < NO) ? n : n - NO;
    Wt[i] = (__bf16)W[k * NO + nn];
}

// ---------------- bf16 MFMA GEMM ----------------
// A [M][128] bf16, Bt [Ncat=2*NO][128] bf16 (transposed concat of Wl,Wr)
// cols 0..NO-1  -> Y bf16 [M][NO]      (lin_l path, no bias)
// cols NO..2NO-1 -> Z fp32 [M][NO] + b (lin_r path)
// block: 128x128 tile of the [M][Ncat] output, 256 threads (4 waves, 2x2)

__global__ __launch_bounds__(256)
void gemm_mfma(const __bf16* __restrict__ A, const __bf16* __restrict__ Bt,
               const float* __restrict__ bias, __bf16* __restrict__ Y,
               float* __restrict__ Z, int M, int NO) {
    __shared__ __bf16 As[128 * 128];
    __shared__ __bf16 Bs[128 * 128];
    const int t = threadIdx.x;
    const int m0 = blockIdx.x * 128;
    const int n0 = blockIdx.y * 128;

    // stage A,B tiles: 128 rows x 256B each; XOR-swizzle 16B chunk index with (row&7)
    #pragma unroll
    for (int it = 0; it < 8; ++it) {
        int r = (t >> 4) + it * 16;
        int c = t & 15;
        int cs = c ^ (r & 7);
        int gm = m0 + r;
        uint4 va = make_uint4(0, 0, 0, 0);
        if (gm < M) va = *(const uint4*)&A[(size_t)gm * 128 + c * 8];
        *(uint4*)&As[r * 128 + cs * 8] = va;
        uint4 vb = *(const uint4*)&Bt[(size_t)(n0 + r) * 128 + c * 8];
        *(uint4*)&Bs[r * 128 + cs * 8] = vb;
    }
    __syncthreads();

    const int w = t >> 6;        // wave 0..3
    const int wm = (w >> 1) * 64;
    const int wn = (w & 1) * 64;
    const int lane = t & 63;
    const int lr = lane & 15;
    const int kg = lane >> 4;    // k-group

    f32_4 acc[4][4] = {};
    #pragma unroll
    for (int ks = 0; ks < 4; ++ks) {
        int kc16 = ks * 4 + kg;  // 16B chunk index along k
        bf16_8 a[4], b[4];
        #pragma unroll
        for (int mi = 0; mi < 4; ++mi) {
            int r = wm + mi * 16 + lr;
            a[mi] = *(const bf16_8*)&As[r * 128 + (kc16 ^ (r & 7)) * 8];
        }
        #pragma unroll
        for (int ni = 0; ni < 4; ++ni) {
            int r = wn + ni * 16 + lr;
            b[ni] = *(const bf16_8*)&Bs[r * 128 + (kc16 ^ (r & 7)) * 8];
        }
        #pragma unroll
        for (int mi = 0; mi < 4; ++mi)
            #pragma unroll
            for (int ni = 0; ni < 4; ++ni)
                acc[mi][ni] = __builtin_amdgcn_mfma_f32_16x16x32_bf16(a[mi], b[ni], acc[mi][ni], 0, 0, 0);
    }

    // epilogue: C/D layout col=lane&15, row=(lane>>4)*4+reg
    #pragma unroll
    for (int mi = 0; mi < 4; ++mi) {
        int gmb = m0 + wm + mi * 16 + kg * 4;
        #pragma unroll
        for (int ni = 0; ni < 4; ++ni) {
            int gc = n0 + wn + ni * 16 + lr;
            bool isY = gc < NO;
            float bv = 0.f;
            if (!isY) bv = bias[gc - NO];
            #pragma unroll
            for (int rr = 0; rr < 4; ++rr) {
                int gm = gmb + rr;
                if (gm < M) {
                    float v = acc[mi][ni][rr] + bv;
                    if (isY) Y[(size_t)gm * NO + gc] = (__bf16)v;
                    else     Z[(size_t)gm * NO + (gc - NO)] = v;
                }
            }
        }
    }
}

// ---------------- aggregation ----------------
// out[v] = relu?( inv[v] * sum_{u in N(v)} y[u] + z[v] )
// y bf16; z fp32; writes hout bf16 (layers 1-2) or fout fp32 (layer 3)
// one wave per destination node

__global__ __launch_bounds__(256)
void agg_kernel(const __bf16* __restrict__ y, const float* __restrict__ z,
                const int* __restrict__ rowstart, const int* __restrict__ col,
                const float* __restrict__ inv, __bf16* __restrict__ hout,
                float* __restrict__ fout, int n, int C, int do_relu) {
    int gw = (int)((blockIdx.x * blockDim.x + threadIdx.x) >> 6);
    int lane = threadIdx.x & 63;
    if (gw >= n) return;
    int beg = rowstart[gw], end = rowstart[gw + 1];
    float iv = inv[gw];
    if (C == 128) {
        float ax = 0.f, ay = 0.f;
        int e = beg;
        for (; e + 4 <= end; e += 4) {
            int u0 = col[e], u1 = col[e + 1], u2 = col[e + 2], u3 = col[e + 3];
            bf16_2 v0 = *(const bf16_2*)&y[(size_t)u0 * 128 + lane * 2];
            bf16_2 v1 = *(const bf16_2*)&y[(size_t)u1 * 128 + lane * 2];
            bf16_2 v2 = *(const bf16_2*)&y[(size_t)u2 * 128 + lane * 2];
            bf16_2 v3 = *(const bf16_2*)&y[(size_t)u3 * 128 + lane * 2];
            ax += (float)v0.x + (float)v1.x + (float)v2.x + (float)v3.x;
            ay += (float)v0.y + (float)v1.y + (float)v2.y + (float)v3.y;
        }
        for (; e < end; ++e) {
            int u = col[e];
            bf16_2 v = *(const bf16_2*)&y[(size_t)u * 128 + lane * 2];
            ax += (float)v.x; ay += (float)v.y;
        }
        float2 zv = *(const float2*)&z[(size_t)gw * 128 + lane * 2];
        float ox = ax * iv + zv.x;
        float oy = ay * iv + zv.y;
        if (do_relu) { ox = fmaxf(ox, 0.f); oy = fmaxf(oy, 0.f); }
        bf16_2 o; o.x = (__bf16)ox; o.y = (__bf16)oy;
        *(bf16_2*)&hout[(size_t)gw * 128 + lane * 2] = o;
    } else {  // C == 64, fp32 final output
        float a = 0.f;
        int e = beg;
        for (; e + 4 <= end; e += 4) {
            int u0 = col[e], u1 = col[e + 1], u2 = col[e + 2], u3 = col[e + 3];
            a += (float)y[(size_t)u0 * 64 + lane] + (float)y[(size_t)u1 * 64 + lane]
               + (float)y[(size_t)u2 * 64 + lane] + (float)y[(size_t)u3 * 64 + lane];
        }
        for (; e < end; ++e) a += (float)y[(size_t)col[e] * 64 + lane];
        float o = a * iv + z[(size_t)gw * 64 + lane];
        fout[(size_t)gw * 64 + lane] = o;
    }
}

// ---------------- launch ----------------

extern "C" void kernel_launch(void* const* d_in, const int* in_sizes, int n_in,
                              void* d_out, int out_size, void* d_ws, size_t ws_size,
                              hipStream_t stream) {
    const float* x   = (const float*)d_in[0];
    const int*   ei  = (const int*)d_in[1];
    const int*   src = ei;
    const int*   dst = ei + NE;
    const float* Wl1 = (const float*)d_in[2];
    const float* Wr1 = (const float*)d_in[3];
    const float* b1  = (const float*)d_in[4];
    const float* Wl2 = (const float*)d_in[5];
    const float* Wr2 = (const float*)d_in[6];
    const float* b2  = (const float*)d_in[7];
    const float* Wl3 = (const float*)d_in[8];
    const float* Wr3 = (const float*)d_in[9];
    const float* b3  = (const float*)d_in[10];
    float* out = (float*)d_out;

    char* ws = (char*)d_ws;
    size_t off = 0;
    auto alloc = [&](size_t bytes) -> void* {
        void* p = ws + off;
        off += (bytes + 255) & ~(size_t)255;
        return p;
    };

    int*    deg      = (int*)alloc(NN * 4);
    int*    incl     = (int*)alloc(NN * 4);
    int*    bsum     = (int*)alloc(64 * 4);
    int*    bbase    = (int*)alloc(64 * 4);
    int*    rowstart = (int*)alloc((NN + 1) * 4);
    int*    cursor   = (int*)alloc(NN * 4);
    int*    col      = (int*)alloc(NE * 4);
    float*  inv      = (float*)alloc(NN * 4);
    __bf16* xb       = (__bf16*)alloc((size_t)NN * 128 * 2);
    __bf16* hb       = (__bf16*)alloc((size_t)NN * 128 * 2);
    __bf16* y        = (__bf16*)alloc((size_t)NN * 128 * 2);
    float*  z        = (float*)alloc((size_t)NN * 128 * 4);
    __bf16* Wt1      = (__bf16*)alloc(256 * 128 * 2);
    __bf16* Wt2      = (__bf16*)alloc(256 * 128 * 2);
    __bf16* Wt3      = (__bf16*)alloc(128 * 128 * 2);

    int nb = (NN + 1023) / 1024;

    hipMemsetAsync(deg, 0, NN * 4, stream);
    deg_kernel<<<(NE + 255) / 256, 256, 0, stream>>>(dst, deg, NE);
    scan_local<<<nb, 1024, 0, stream>>>(deg, incl, bsum, NN);
    scan_bases<<<1, 64, 0, stream>>>(bsum, bbase, nb);
    scan_final<<<nb, 1024, 0, stream>>>(deg, incl, bbase, rowstart, cursor, inv, NN, NE);
    fill_kernel<<<(NE + 255) / 256, 256, 0, stream>>>(src, dst, cursor, col, NE);

    convx_kernel<<<(NN * 128 / 4 + 255) / 256, 256, 0, stream>>>(x, xb, NN * 128);
    convw_kernel<<<(256 * 128 + 255) / 256, 256, 0, stream>>>(Wl1, Wr1, Wt1, 128);
    convw_kernel<<<(256 * 128 + 255) / 256, 256, 0, stream>>>(Wl2, Wr2, Wt2, 128);
    convw_kernel<<<(128 * 128 + 255) / 256, 256, 0, stream>>>(Wl3, Wr3, Wt3, 64);

    int mblocks = (NN + 127) / 128;
    int aggBlocks = (NN * 64) / 256;

    // layer 1
    gemm_mfma<<<dim3(mblocks, 2), 256, 0, stream>>>(xb, Wt1, b1, y, z, NN, 128);
    agg_kernel<<<aggBlocks, 256, 0, stream>>>(y, z, rowstart, col, inv, hb, nullptr, NN, 128, 1);
    // layer 2
    gemm_mfma<<<dim3(mblocks, 2), 256, 0, stream>>>(hb, Wt2, b2, y, z, NN, 128);
    agg_kernel<<<aggBlocks, 256, 0, stream>>>(y, z, rowstart, col, inv, hb, nullptr, NN, 128, 1);
    // layer 3
    gemm_mfma<<<dim3(mblocks, 1), 256, 0, stream>>>(hb, Wt3, b3, y, z, NN, 64);
    agg_kernel<<<aggBlocks, 256, 0, stream>>>(y, z, rowstart, col, inv, nullptr, out, NN, 64, 0);
}

// Round 3
// 241.228 us; speedup vs baseline: 1.8203x; 1.1006x over previous
//
#include <hip/hip_runtime.h>

#define NN 50000
#define NE 625000

typedef __bf16 bf16_8 __attribute__((ext_vector_type(8)));
typedef __bf16 bf16_4 __attribute__((ext_vector_type(4)));
typedef __bf16 bf16_2 __attribute__((ext_vector_type(2)));
typedef float f32_4 __attribute__((ext_vector_type(4)));

// ---------------- CSR build ----------------

__global__ void deg_kernel(const int* __restrict__ dst, int* __restrict__ deg, int e) {
    int i = blockIdx.x * blockDim.x + threadIdx.x;
    if (i < e) atomicAdd(&deg[dst[i]], 1);
}

__global__ void scan_local(const int* __restrict__ deg, int* __restrict__ incl,
                           int* __restrict__ bsum, int n) {
    __shared__ int s[1024];
    int i = blockIdx.x * 1024 + threadIdx.x;
    int v = (i < n) ? deg[i] : 0;
    s[threadIdx.x] = v;
    __syncthreads();
    for (int off = 1; off < 1024; off <<= 1) {
        int t = (threadIdx.x >= (unsigned)off) ? s[threadIdx.x - off] : 0;
        __syncthreads();
        s[threadIdx.x] += t;
        __syncthreads();
    }
    if (i < n) incl[i] = s[threadIdx.x];
    if (threadIdx.x == 1023) bsum[blockIdx.x] = s[1023];
}

__global__ void scan_bases(const int* __restrict__ bsum, int* __restrict__ bbase, int nb) {
    int lane = threadIdx.x;
    int v = (lane < nb) ? bsum[lane] : 0;
    int orig = v;
    for (int off = 1; off < 64; off <<= 1) {
        int t = __shfl_up(v, off, 64);
        if (lane >= off) v += t;
    }
    if (lane < nb) bbase[lane] = v - orig;
}

__global__ void scan_final(const int* __restrict__ deg, const int* __restrict__ incl,
                           const int* __restrict__ bbase, int* __restrict__ rowstart,
                           int* __restrict__ cursor, float* __restrict__ inv, int n, int e) {
    int i = blockIdx.x * 1024 + threadIdx.x;
    if (i < n) {
        int v = deg[i];
        int excl = bbase[blockIdx.x] + incl[i] - v;
        rowstart[i] = excl;
        cursor[i] = excl;
        inv[i] = 1.0f / (float)max(v, 1);
    }
    if (i == 0) rowstart[n] = e;
}

__global__ void fill_kernel(const int* __restrict__ src, const int* __restrict__ dst,
                            int* __restrict__ cursor, int* __restrict__ col, int e) {
    int i = blockIdx.x * blockDim.x + threadIdx.x;
    if (i < e) {
        int p = atomicAdd(&cursor[dst[i]], 1);
        col[p] = src[i];
    }
}

// ---------------- weight convert: all three layers in one dispatch ----------------
// Wl[K=128][NO], Wr[K=128][NO] fp32 -> Wt[2*NO][128] bf16 transposed concat

__device__ __forceinline__ void convw_one(const float* Wl, const float* Wr,
                                          __bf16* Wt, int NO, int i) {
    int k = i & 127;
    int n = i >> 7;
    const float* W = (n < NO) ? Wl : Wr;
    int nn = (n < NO) ? n : n - NO;
    Wt[i] = (__bf16)W[k * NO + nn];
}

__global__ void convw_all(const float* __restrict__ Wl1, const float* __restrict__ Wr1, __bf16* __restrict__ Wt1,
                          const float* __restrict__ Wl2, const float* __restrict__ Wr2, __bf16* __restrict__ Wt2,
                          const float* __restrict__ Wl3, const float* __restrict__ Wr3, __bf16* __restrict__ Wt3) {
    int i = blockIdx.x * blockDim.x + threadIdx.x;
    if (i < 32768)       convw_one(Wl1, Wr1, Wt1, 128, i);
    else if (i < 65536)  convw_one(Wl2, Wr2, Wt2, 128, i - 32768);
    else if (i < 81920)  convw_one(Wl3, Wr3, Wt3, 64, i - 65536);
}

// ---------------- bf16 MFMA GEMM ----------------
// A [M][128] (fp32 if AF32 else bf16), Bt [2*NO][128] bf16 (transposed concat Wl|Wr)
// cols 0..NO-1    -> Y bf16 [M][NO]                (lin_l path, no bias)
// cols NO..2NO-1  -> Z [M][NO] + bias              (lin_r path; bf16 or fp32 per ZF32)
// block: 128x128 output tile, 256 threads (4 waves 2x2), whole K=128 in LDS

template<int AF32, int ZF32>
__global__ __launch_bounds__(256)
void gemm_mfma(const void* __restrict__ Ap, const __bf16* __restrict__ Bt,
               const float* __restrict__ bias, __bf16* __restrict__ Y,
               void* __restrict__ Zp, int M, int NO) {
    __shared__ __bf16 As[128 * 128];
    __shared__ __bf16 Bs[128 * 128];
    const int t = threadIdx.x;
    const int m0 = blockIdx.x * 128;
    const int n0 = blockIdx.y * 128;

    // stage A,B tiles: 128 rows x 256B; XOR-swizzle 16B chunk index with (row&7)
    #pragma unroll
    for (int it = 0; it < 8; ++it) {
        int r = (t >> 4) + it * 16;
        int c = t & 15;
        int cs = c ^ (r & 7);
        int gm = m0 + r;
        if (AF32) {
            const float* A32 = (const float*)Ap;
            float4 lo = make_float4(0.f, 0.f, 0.f, 0.f), hi = lo;
            if (gm < M) {
                lo = *(const float4*)&A32[(size_t)gm * 128 + c * 8];
                hi = *(const float4*)&A32[(size_t)gm * 128 + c * 8 + 4];
            }
            bf16_8 v;
            v[0] = (__bf16)lo.x; v[1] = (__bf16)lo.y; v[2] = (__bf16)lo.z; v[3] = (__bf16)lo.w;
            v[4] = (__bf16)hi.x; v[5] = (__bf16)hi.y; v[6] = (__bf16)hi.z; v[7] = (__bf16)hi.w;
            *(bf16_8*)&As[r * 128 + cs * 8] = v;
        } else {
            const __bf16* Ab = (const __bf16*)Ap;
            uint4 va = make_uint4(0, 0, 0, 0);
            if (gm < M) va = *(const uint4*)&Ab[(size_t)gm * 128 + c * 8];
            *(uint4*)&As[r * 128 + cs * 8] = va;
        }
        uint4 vb = *(const uint4*)&Bt[(size_t)(n0 + r) * 128 + c * 8];
        *(uint4*)&Bs[r * 128 + cs * 8] = vb;
    }
    __syncthreads();

    const int w = t >> 6;
    const int wm = (w >> 1) * 64;
    const int wn = (w & 1) * 64;
    const int lane = t & 63;
    const int lr = lane & 15;
    const int kg = lane >> 4;

    f32_4 acc[4][4] = {};
    #pragma unroll
    for (int ks = 0; ks < 4; ++ks) {
        int kc16 = ks * 4 + kg;
        bf16_8 a[4], b[4];
        #pragma unroll
        for (int mi = 0; mi < 4; ++mi) {
            int r = wm + mi * 16 + lr;
            a[mi] = *(const bf16_8*)&As[r * 128 + (kc16 ^ (r & 7)) * 8];
        }
        #pragma unroll
        for (int ni = 0; ni < 4; ++ni) {
            int r = wn + ni * 16 + lr;
            b[ni] = *(const bf16_8*)&Bs[r * 128 + (kc16 ^ (r & 7)) * 8];
        }
        #pragma unroll
        for (int mi = 0; mi < 4; ++mi)
            #pragma unroll
            for (int ni = 0; ni < 4; ++ni)
                acc[mi][ni] = __builtin_amdgcn_mfma_f32_16x16x32_bf16(a[mi], b[ni], acc[mi][ni], 0, 0, 0);
    }

    // epilogue: C/D layout col=lane&15, row=(lane>>4)*4+reg
    #pragma unroll
    for (int mi = 0; mi < 4; ++mi) {
        int gmb = m0 + wm + mi * 16 + kg * 4;
        #pragma unroll
        for (int ni = 0; ni < 4; ++ni) {
            int gc = n0 + wn + ni * 16 + lr;
            bool isY = gc < NO;
            float bv = 0.f;
            if (!isY) bv = bias[gc - NO];
            #pragma unroll
            for (int rr = 0; rr < 4; ++rr) {
                int gm = gmb + rr;
                if (gm < M) {
                    float v = acc[mi][ni][rr] + bv;
                    if (isY) Y[(size_t)gm * NO + gc] = (__bf16)v;
                    else if (ZF32) ((float*)Zp)[(size_t)gm * NO + (gc - NO)] = v;
                    else ((__bf16*)Zp)[(size_t)gm * NO + (gc - NO)] = (__bf16)v;
                }
            }
        }
    }
}

// ---------------- aggregation ----------------
// one wave per dst node, 4x 16-lane groups gather 4 neighbor rows/iter

__global__ __launch_bounds__(256)
void agg128_kernel(const __bf16* __restrict__ y, const __bf16* __restrict__ z,
                   const int* __restrict__ rowstart, const int* __restrict__ col,
                   const float* __restrict__ inv, __bf16* __restrict__ hout, int n) {
    int gw = (int)((blockIdx.x * blockDim.x + threadIdx.x) >> 6);
    if (gw >= n) return;
    int lane = threadIdx.x & 63;
    int s = lane & 15, g = lane >> 4;
    int beg = rowstart[gw], end = rowstart[gw + 1];
    float iv = inv[gw];
    float acc[8] = {};
    for (int e0 = beg; e0 < end; e0 += 8) {
        int e1 = e0 + g, e2 = e0 + 4 + g;
        bf16_8 v1 = {}, v2 = {};
        if (e1 < end) { int u = col[e1]; v1 = *(const bf16_8*)&y[(size_t)u * 128 + s * 8]; }
        if (e2 < end) { int u = col[e2]; v2 = *(const bf16_8*)&y[(size_t)u * 128 + s * 8]; }
        #pragma unroll
        for (int j = 0; j < 8; ++j) acc[j] += (float)v1[j] + (float)v2[j];
    }
    #pragma unroll
    for (int j = 0; j < 8; ++j) {
        acc[j] += __shfl_xor(acc[j], 16, 64);
        acc[j] += __shfl_xor(acc[j], 32, 64);
    }
    if (g == 0) {
        bf16_8 zv = *(const bf16_8*)&z[(size_t)gw * 128 + s * 8];
        bf16_8 o;
        #pragma unroll
        for (int j = 0; j < 8; ++j) {
            float v = acc[j] * iv + (float)zv[j];
            o[j] = (__bf16)fmaxf(v, 0.f);
        }
        *(bf16_8*)&hout[(size_t)gw * 128 + s * 8] = o;
    }
}

__global__ __launch_bounds__(256)
void agg64_kernel(const __bf16* __restrict__ y, const float* __restrict__ z,
                  const int* __restrict__ rowstart, const int* __restrict__ col,
                  const float* __restrict__ inv, float* __restrict__ fout, int n) {
    int gw = (int)((blockIdx.x * blockDim.x + threadIdx.x) >> 6);
    if (gw >= n) return;
    int lane = threadIdx.x & 63;
    int s = lane & 15, g = lane >> 4;
    int beg = rowstart[gw], end = rowstart[gw + 1];
    float iv = inv[gw];
    float acc[4] = {};
    for (int e0 = beg; e0 < end; e0 += 8) {
        int e1 = e0 + g, e2 = e0 + 4 + g;
        bf16_4 v1 = {}, v2 = {};
        if (e1 < end) { int u = col[e1]; v1 = *(const bf16_4*)&y[(size_t)u * 64 + s * 4]; }
        if (e2 < end) { int u = col[e2]; v2 = *(const bf16_4*)&y[(size_t)u * 64 + s * 4]; }
        #pragma unroll
        for (int j = 0; j < 4; ++j) acc[j] += (float)v1[j] + (float)v2[j];
    }
    #pragma unroll
    for (int j = 0; j < 4; ++j) {
        acc[j] += __shfl_xor(acc[j], 16, 64);
        acc[j] += __shfl_xor(acc[j], 32, 64);
    }
    if (g == 0) {
        float4 zv = *(const float4*)&z[(size_t)gw * 64 + s * 4];
        float4 o;
        o.x = acc[0] * iv + zv.x;
        o.y = acc[1] * iv + zv.y;
        o.z = acc[2] * iv + zv.z;
        o.w = acc[3] * iv + zv.w;
        *(float4*)&fout[(size_t)gw * 64 + s * 4] = o;
    }
}

// ---------------- launch ----------------

extern "C" void kernel_launch(void* const* d_in, const int* in_sizes, int n_in,
                              void* d_out, int out_size, void* d_ws, size_t ws_size,
                              hipStream_t stream) {
    const float* x   = (const float*)d_in[0];
    const int*   ei  = (const int*)d_in[1];
    const int*   src = ei;
    const int*   dst = ei + NE;
    const float* Wl1 = (const float*)d_in[2];
    const float* Wr1 = (const float*)d_in[3];
    const float* b1  = (const float*)d_in[4];
    const float* Wl2 = (const float*)d_in[5];
    const float* Wr2 = (const float*)d_in[6];
    const float* b2  = (const float*)d_in[7];
    const float* Wl3 = (const float*)d_in[8];
    const float* Wr3 = (const float*)d_in[9];
    const float* b3  = (const float*)d_in[10];
    float* out = (float*)d_out;

    char* ws = (char*)d_ws;
    size_t off = 0;
    auto alloc = [&](size_t bytes) -> void* {
        void* p = ws + off;
        off += (bytes + 255) & ~(size_t)255;
        return p;
    };

    int*    deg      = (int*)alloc(NN * 4);
    int*    incl     = (int*)alloc(NN * 4);
    int*    bsum     = (int*)alloc(64 * 4);
    int*    bbase    = (int*)alloc(64 * 4);
    int*    rowstart = (int*)alloc((NN + 1) * 4);
    int*    cursor   = (int*)alloc(NN * 4);
    int*    col      = (int*)alloc(NE * 4);
    float*  inv      = (float*)alloc(NN * 4);
    __bf16* hb       = (__bf16*)alloc((size_t)NN * 128 * 2);
    __bf16* y        = (__bf16*)alloc((size_t)NN * 128 * 2);
    __bf16* zb       = (__bf16*)alloc((size_t)NN * 128 * 2);
    float*  zf       = (float*)alloc((size_t)NN * 64 * 4);
    __bf16* Wt1      = (__bf16*)alloc(256 * 128 * 2);
    __bf16* Wt2      = (__bf16*)alloc(256 * 128 * 2);
    __bf16* Wt3      = (__bf16*)alloc(128 * 128 * 2);

    int nb = (NN + 1023) / 1024;

    hipMemsetAsync(deg, 0, NN * 4, stream);
    deg_kernel<<<(NE + 255) / 256, 256, 0, stream>>>(dst, deg, NE);
    scan_local<<<nb, 1024, 0, stream>>>(deg, incl, bsum, NN);
    scan_bases<<<1, 64, 0, stream>>>(bsum, bbase, nb);
    scan_final<<<nb, 1024, 0, stream>>>(deg, incl, bbase, rowstart, cursor, inv, NN, NE);
    fill_kernel<<<(NE + 255) / 256, 256, 0, stream>>>(src, dst, cursor, col, NE);
    convw_all<<<320, 256, 0, stream>>>(Wl1, Wr1, Wt1, Wl2, Wr2, Wt2, Wl3, Wr3, Wt3);

    int mblocks = (NN + 127) / 128;
    int aggBlocks = (NN * 64) / 256;

    // layer 1 (A = x fp32, Z bf16)
    gemm_mfma<1, 0><<<dim3(mblocks, 2), 256, 0, stream>>>(x, Wt1, b1, y, zb, NN, 128);
    agg128_kernel<<<aggBlocks, 256, 0, stream>>>(y, zb, rowstart, col, inv, hb, NN);
    // layer 2 (A = hb bf16, Z bf16)
    gemm_mfma<0, 0><<<dim3(mblocks, 2), 256, 0, stream>>>(hb, Wt2, b2, y, zb, NN, 128);
    agg128_kernel<<<aggBlocks, 256, 0, stream>>>(y, zb, rowstart, col, inv, hb, NN);
    // layer 3 (A = hb bf16, Z fp32)
    gemm_mfma<0, 1><<<dim3(mblocks, 1), 256, 0, stream>>>(hb, Wt3, b3, y, zf, NN, 64);
    agg64_kernel<<<aggBlocks, 256, 0, stream>>>(y, zf, rowstart, col, inv, out, NN);
}

// Round 4
// 221.105 us; speedup vs baseline: 1.9860x; 1.0910x over previous
//
#include <hip/hip_runtime.h>

#define NN 50000
#define NE 625000
#define NB 49  // ceil(NN/1024)

typedef __bf16 bf16_8 __attribute__((ext_vector_type(8)));
typedef __bf16 bf16_4 __attribute__((ext_vector_type(4)));
typedef float f32_4 __attribute__((ext_vector_type(4)));

// ---------------- K1: zero counters + convert all weights ----------------
// Wl[K=128][NO], Wr[K=128][NO] fp32 -> Wt[2*NO][128] bf16 transposed concat

__device__ __forceinline__ void convw_one(const float* Wl, const float* Wr,
                                          __bf16* Wt, int NO, int i) {
    int k = i & 127;
    int n = i >> 7;
    const float* W = (n < NO) ? Wl : Wr;
    int nn = (n < NO) ? n : n - NO;
    Wt[i] = (__bf16)W[k * NO + nn];
}

__global__ void init_kernel(int* __restrict__ deg, unsigned long long* __restrict__ state,
                            int* __restrict__ vcounter, int* __restrict__ rowstart,
                            const float* __restrict__ Wl1, const float* __restrict__ Wr1, __bf16* __restrict__ Wt1,
                            const float* __restrict__ Wl2, const float* __restrict__ Wr2, __bf16* __restrict__ Wt2,
                            const float* __restrict__ Wl3, const float* __restrict__ Wr3, __bf16* __restrict__ Wt3) {
    int i = blockIdx.x * blockDim.x + threadIdx.x;
    if (i < NN) deg[i] = 0;
    if (i < NB) state[i] = 0ull;
    if (i == 0) { *vcounter = 0; rowstart[NN] = NE; }
    if (i < 32768)      convw_one(Wl1, Wr1, Wt1, 128, i);
    else if (i < 65536) convw_one(Wl2, Wr2, Wt2, 128, i - 32768);
    else if (i < 81920) convw_one(Wl3, Wr3, Wt3, 64, i - 65536);
}

// ---------------- K2: degree count ----------------

__global__ void deg_kernel(const int* __restrict__ dst, int* __restrict__ deg, int e) {
    int i = blockIdx.x * blockDim.x + threadIdx.x;
    if (i < e) atomicAdd(&deg[dst[i]], 1);
}

// ---------------- K3: single-pass decoupled-lookback scan ----------------
// produces rowstart (exclusive), cursor copy, inv = 1/max(deg,1)

__global__ __launch_bounds__(1024)
void scan_kernel(const int* __restrict__ deg, int* __restrict__ rowstart,
                 int* __restrict__ cursor, float* __restrict__ inv,
                 unsigned long long* __restrict__ state, int* __restrict__ vcounter) {
    __shared__ int s[1024];
    __shared__ int s_vb, s_base;
    int tid = threadIdx.x;
    if (tid == 0) s_vb = atomicAdd(vcounter, 1);
    __syncthreads();
    int vb = s_vb;
    int i = vb * 1024 + tid;
    int v = (i < NN) ? deg[i] : 0;
    s[tid] = v;
    __syncthreads();
    for (int off = 1; off < 1024; off <<= 1) {
        int t = (tid >= off) ? s[tid - off] : 0;
        __syncthreads();
        s[tid] += t;
        __syncthreads();
    }
    int incl = s[tid];
    int agg = s[1023];
    if (tid == 0) {
        if (vb == 0) {
            atomicExch(&state[0], (2ull << 62) | (unsigned long long)(unsigned)agg);
            s_base = 0;
        } else {
            atomicExch(&state[vb], (1ull << 62) | (unsigned long long)(unsigned)agg);
            int base = 0;
            int p = vb - 1;
            while (p >= 0) {
                unsigned long long st;
                do { st = atomicAdd(&state[p], 0ull); } while ((st >> 62) == 0ull);
                base += (int)(unsigned)(st & 0xffffffffull);
                if ((st >> 62) == 2ull) break;
                --p;
            }
            atomicExch(&state[vb], (2ull << 62) | (unsigned long long)(unsigned)(base + agg));
            s_base = base;
        }
    }
    __syncthreads();
    int base = s_base;
    if (i < NN) {
        int excl = base + incl - v;
        rowstart[i] = excl;
        cursor[i] = excl;
        inv[i] = 1.0f / (float)max(v, 1);
    }
}

// ---------------- K4: CSR fill ----------------

__global__ void fill_kernel(const int* __restrict__ src, const int* __restrict__ dst,
                            int* __restrict__ cursor, int* __restrict__ col, int e) {
    int i = blockIdx.x * blockDim.x + threadIdx.x;
    if (i < e) {
        int p = atomicAdd(&cursor[dst[i]], 1);
        col[p] = src[i];
    }
}

// ---------------- bf16 MFMA GEMM ----------------
// A [M][128] (fp32 if AF32 else bf16), Bt [2*NO][128] bf16 (transposed concat Wl|Wr)
// cols 0..NO-1    -> Y bf16 [M][NO]      (lin_l path, no bias)
// cols NO..2NO-1  -> Z [M][NO] + bias    (lin_r path; bf16 or fp32 per ZF32)

template<int AF32, int ZF32>
__global__ __launch_bounds__(256)
void gemm_mfma(const void* __restrict__ Ap, const __bf16* __restrict__ Bt,
               const float* __restrict__ bias, __bf16* __restrict__ Y,
               void* __restrict__ Zp, int M, int NO) {
    __shared__ __bf16 As[128 * 128];
    __shared__ __bf16 Bs[128 * 128];
    const int t = threadIdx.x;
    const int m0 = blockIdx.x * 128;
    const int n0 = blockIdx.y * 128;

    #pragma unroll
    for (int it = 0; it < 8; ++it) {
        int r = (t >> 4) + it * 16;
        int c = t & 15;
        int cs = c ^ (r & 7);
        int gm = m0 + r;
        if (AF32) {
            const float* A32 = (const float*)Ap;
            float4 lo = make_float4(0.f, 0.f, 0.f, 0.f), hi = lo;
            if (gm < M) {
                lo = *(const float4*)&A32[(size_t)gm * 128 + c * 8];
                hi = *(const float4*)&A32[(size_t)gm * 128 + c * 8 + 4];
            }
            bf16_8 v;
            v[0] = (__bf16)lo.x; v[1] = (__bf16)lo.y; v[2] = (__bf16)lo.z; v[3] = (__bf16)lo.w;
            v[4] = (__bf16)hi.x; v[5] = (__bf16)hi.y; v[6] = (__bf16)hi.z; v[7] = (__bf16)hi.w;
            *(bf16_8*)&As[r * 128 + cs * 8] = v;
        } else {
            const __bf16* Ab = (const __bf16*)Ap;
            uint4 va = make_uint4(0, 0, 0, 0);
            if (gm < M) va = *(const uint4*)&Ab[(size_t)gm * 128 + c * 8];
            *(uint4*)&As[r * 128 + cs * 8] = va;
        }
        uint4 vb = *(const uint4*)&Bt[(size_t)(n0 + r) * 128 + c * 8];
        *(uint4*)&Bs[r * 128 + cs * 8] = vb;
    }
    __syncthreads();

    const int w = t >> 6;
    const int wm = (w >> 1) * 64;
    const int wn = (w & 1) * 64;
    const int lane = t & 63;
    const int lr = lane & 15;
    const int kg = lane >> 4;

    f32_4 acc[4][4] = {};
    #pragma unroll
    for (int ks = 0; ks < 4; ++ks) {
        int kc16 = ks * 4 + kg;
        bf16_8 a[4], b[4];
        #pragma unroll
        for (int mi = 0; mi < 4; ++mi) {
            int r = wm + mi * 16 + lr;
            a[mi] = *(const bf16_8*)&As[r * 128 + (kc16 ^ (r & 7)) * 8];
        }
        #pragma unroll
        for (int ni = 0; ni < 4; ++ni) {
            int r = wn + ni * 16 + lr;
            b[ni] = *(const bf16_8*)&Bs[r * 128 + (kc16 ^ (r & 7)) * 8];
        }
        #pragma unroll
        for (int mi = 0; mi < 4; ++mi)
            #pragma unroll
            for (int ni = 0; ni < 4; ++ni)
                acc[mi][ni] = __builtin_amdgcn_mfma_f32_16x16x32_bf16(a[mi], b[ni], acc[mi][ni], 0, 0, 0);
    }

    #pragma unroll
    for (int mi = 0; mi < 4; ++mi) {
        int gmb = m0 + wm + mi * 16 + kg * 4;
        #pragma unroll
        for (int ni = 0; ni < 4; ++ni) {
            int gc = n0 + wn + ni * 16 + lr;
            bool isY = gc < NO;
            float bv = 0.f;
            if (!isY) bv = bias[gc - NO];
            #pragma unroll
            for (int rr = 0; rr < 4; ++rr) {
                int gm = gmb + rr;
                if (gm < M) {
                    float v = acc[mi][ni][rr] + bv;
                    if (isY) Y[(size_t)gm * NO + gc] = (__bf16)v;
                    else if (ZF32) ((float*)Zp)[(size_t)gm * NO + (gc - NO)] = v;
                    else ((__bf16*)Zp)[(size_t)gm * NO + (gc - NO)] = (__bf16)v;
                }
            }
        }
    }
}

// ---------------- aggregation: one 16-lane group per dst node ----------------
// out[v] = relu?( inv[v] * sum_{u in N(v)} y[u] + z[v] )

__global__ __launch_bounds__(256)
void agg128_kernel(const __bf16* __restrict__ y, const __bf16* __restrict__ z,
                   const int* __restrict__ rowstart, const int* __restrict__ col,
                   const float* __restrict__ inv, __bf16* __restrict__ hout, int n) {
    int gid = blockIdx.x * 16 + (threadIdx.x >> 4);
    if (gid >= n) return;
    int s = threadIdx.x & 15;
    int beg = rowstart[gid], end = rowstart[gid + 1];
    float iv = inv[gid];
    float acc[8] = {};
    for (int e0 = beg; e0 < end; e0 += 4) {
        int u0 = col[e0];
        int u1 = (e0 + 1 < end) ? col[e0 + 1] : -1;
        int u2 = (e0 + 2 < end) ? col[e0 + 2] : -1;
        int u3 = (e0 + 3 < end) ? col[e0 + 3] : -1;
        bf16_8 v0 = *(const bf16_8*)&y[(size_t)u0 * 128 + s * 8];
        bf16_8 v1 = {}, v2 = {}, v3 = {};
        if (u1 >= 0) v1 = *(const bf16_8*)&y[(size_t)u1 * 128 + s * 8];
        if (u2 >= 0) v2 = *(const bf16_8*)&y[(size_t)u2 * 128 + s * 8];
        if (u3 >= 0) v3 = *(const bf16_8*)&y[(size_t)u3 * 128 + s * 8];
        #pragma unroll
        for (int j = 0; j < 8; ++j)
            acc[j] += ((float)v0[j] + (float)v1[j]) + ((float)v2[j] + (float)v3[j]);
    }
    bf16_8 zv = *(const bf16_8*)&z[(size_t)gid * 128 + s * 8];
    bf16_8 o;
    #pragma unroll
    for (int j = 0; j < 8; ++j) {
        float v = acc[j] * iv + (float)zv[j];
        o[j] = (__bf16)fmaxf(v, 0.f);
    }
    *(bf16_8*)&hout[(size_t)gid * 128 + s * 8] = o;
}

__global__ __launch_bounds__(256)
void agg64_kernel(const __bf16* __restrict__ y, const float* __restrict__ z,
                  const int* __restrict__ rowstart, const int* __restrict__ col,
                  const float* __restrict__ inv, float* __restrict__ fout, int n) {
    int gid = blockIdx.x * 16 + (threadIdx.x >> 4);
    if (gid >= n) return;
    int s = threadIdx.x & 15;
    int beg = rowstart[gid], end = rowstart[gid + 1];
    float iv = inv[gid];
    float acc[4] = {};
    for (int e0 = beg; e0 < end; e0 += 4) {
        int u0 = col[e0];
        int u1 = (e0 + 1 < end) ? col[e0 + 1] : -1;
        int u2 = (e0 + 2 < end) ? col[e0 + 2] : -1;
        int u3 = (e0 + 3 < end) ? col[e0 + 3] : -1;
        bf16_4 v0 = *(const bf16_4*)&y[(size_t)u0 * 64 + s * 4];
        bf16_4 v1 = {}, v2 = {}, v3 = {};
        if (u1 >= 0) v1 = *(const bf16_4*)&y[(size_t)u1 * 64 + s * 4];
        if (u2 >= 0) v2 = *(const bf16_4*)&y[(size_t)u2 * 64 + s * 4];
        if (u3 >= 0) v3 = *(const bf16_4*)&y[(size_t)u3 * 64 + s * 4];
        #pragma unroll
        for (int j = 0; j < 4; ++j)
            acc[j] += ((float)v0[j] + (float)v1[j]) + ((float)v2[j] + (float)v3[j]);
    }
    float4 zv = *(const float4*)&z[(size_t)gid * 64 + s * 4];
    float4 o;
    o.x = acc[0] * iv + zv.x;
    o.y = acc[1] * iv + zv.y;
    o.z = acc[2] * iv + zv.z;
    o.w = acc[3] * iv + zv.w;
    *(float4*)&fout[(size_t)gid * 64 + s * 4] = o;
}

// ---------------- launch ----------------

extern "C" void kernel_launch(void* const* d_in, const int* in_sizes, int n_in,
                              void* d_out, int out_size, void* d_ws, size_t ws_size,
                              hipStream_t stream) {
    const float* x   = (const float*)d_in[0];
    const int*   ei  = (const int*)d_in[1];
    const int*   src = ei;
    const int*   dst = ei + NE;
    const float* Wl1 = (const float*)d_in[2];
    const float* Wr1 = (const float*)d_in[3];
    const float* b1  = (const float*)d_in[4];
    const float* Wl2 = (const float*)d_in[5];
    const float* Wr2 = (const float*)d_in[6];
    const float* b2  = (const float*)d_in[7];
    const float* Wl3 = (const float*)d_in[8];
    const float* Wr3 = (const float*)d_in[9];
    const float* b3  = (const float*)d_in[10];
    float* out = (float*)d_out;

    char* ws = (char*)d_ws;
    size_t off = 0;
    auto alloc = [&](size_t bytes) -> void* {
        void* p = ws + off;
        off += (bytes + 255) & ~(size_t)255;
        return p;
    };

    int*    deg      = (int*)alloc(NN * 4);
    int*    rowstart = (int*)alloc((NN + 1) * 4);
    int*    cursor   = (int*)alloc(NN * 4);
    int*    col      = (int*)alloc(NE * 4);
    float*  inv      = (float*)alloc(NN * 4);
    unsigned long long* state = (unsigned long long*)alloc(NB * 8);
    int*    vcounter = (int*)alloc(4);
    __bf16* hb       = (__bf16*)alloc((size_t)NN * 128 * 2);
    __bf16* y        = (__bf16*)alloc((size_t)NN * 128 * 2);
    __bf16* zb       = (__bf16*)alloc((size_t)NN * 128 * 2);
    float*  zf       = (float*)alloc((size_t)NN * 64 * 4);
    __bf16* Wt1      = (__bf16*)alloc(256 * 128 * 2);
    __bf16* Wt2      = (__bf16*)alloc(256 * 128 * 2);
    __bf16* Wt3     = (__bf16*)alloc(128 * 128 * 2);

    init_kernel<<<320, 256, 0, stream>>>(deg, state, vcounter, rowstart,
                                         Wl1, Wr1, Wt1, Wl2, Wr2, Wt2, Wl3, Wr3, Wt3);
    deg_kernel<<<(NE + 255) / 256, 256, 0, stream>>>(dst, deg, NE);
    scan_kernel<<<NB, 1024, 0, stream>>>(deg, rowstart, cursor, inv, state, vcounter);
    fill_kernel<<<(NE + 255) / 256, 256, 0, stream>>>(src, dst, cursor, col, NE);

    int mblocks = (NN + 127) / 128;
    int aggBlocks = (NN + 15) / 16;

    // layer 1 (A = x fp32, Z bf16)
    gemm_mfma<1, 0><<<dim3(mblocks, 2), 256, 0, stream>>>(x, Wt1, b1, y, zb, NN, 128);
    agg128_kernel<<<aggBlocks, 256, 0, stream>>>(y, zb, rowstart, col, inv, hb, NN);
    // layer 2 (A = hb bf16, Z bf16)
    gemm_mfma<0, 0><<<dim3(mblocks, 2), 256, 0, stream>>>(hb, Wt2, b2, y, zb, NN, 128);
    agg128_kernel<<<aggBlocks, 256, 0, stream>>>(y, zb, rowstart, col, inv, hb, NN);
    // layer 3 (A = hb bf16, Z fp32)
    gemm_mfma<0, 1><<<dim3(mblocks, 1), 256, 0, stream>>>(hb, Wt3, b3, y, zf, NN, 64);
    agg64_kernel<<<aggBlocks, 256, 0, stream>>>(y, zf, rowstart, col, inv, out, NN);
}